// Round 12
// baseline (5211.959 us; speedup 1.0000x reference)
//
#include <hip/hip_runtime.h>
#include <stdint.h>

#define TT 256
#define BB 64
#define DD 1024
#define HH 1024
#define G3 3072

typedef unsigned long long ull;
typedef __attribute__((ext_vector_type(8))) short short8;
typedef __attribute__((ext_vector_type(4))) float f32x4;

__device__ __forceinline__ unsigned short f2bf(float f) {
  union { float f; unsigned int i; } v; v.f = f;
  unsigned int x = v.i;
  return (unsigned short)((x + 0x7fffu + ((x >> 16) & 1u)) >> 16);
}
__device__ __forceinline__ float bf2f(unsigned short u) {
  union { unsigned int i; float f; } v; v.i = ((unsigned int)u) << 16; return v.f;
}
__device__ __forceinline__ f32x4 mfma16(short8 a, short8 b, f32x4 c) {
  return __builtin_amdgcn_mfma_f32_16x16x32_bf16(a, b, c, 0, 0, 0);
}
__device__ __forceinline__ void gload_lds16(const void* g, void* l) {
  __builtin_amdgcn_global_load_lds((const __attribute__((address_space(1))) void*)g,
                                   (__attribute__((address_space(3))) void*)l,
                                   16, 0, 0);
}
// packed f32x2 -> bf16x2 (RTNE). Non-volatile: pure reg function, schedulable;
// register deps force correct waitcnt insertion before use.
__device__ __forceinline__ unsigned int cvtpk(float a, float b) {
  unsigned int r;
  asm("v_cvt_pk_bf16_f32 %0, %1, %2" : "=v"(r) : "v"(a), "v"(b));
  return r;
}
__device__ __forceinline__ short8 pack8(float4 f0, float4 f1) {
  union { unsigned int u[4]; short8 v; } r;
  r.u[0] = cvtpk(f0.x, f0.y);
  r.u[1] = cvtpk(f0.z, f0.w);
  r.u[2] = cvtpk(f1.x, f1.y);
  r.u[3] = cvtpk(f1.z, f1.w);
  return r.v;
}

// ---------------- f32 -> bf16 convert (vectorized) ----------------
__global__ void k_cvt_bf16(const float* __restrict__ in, unsigned short* __restrict__ out, int n4) {
  int i = blockIdx.x * blockDim.x + threadIdx.x;
  int stride = gridDim.x * blockDim.x;
  for (; i < n4; i += stride) {
    float4 v = ((const float4*)in)[i];
    ushort4 o;
    o.x = f2bf(v.x); o.y = f2bf(v.y); o.z = f2bf(v.z); o.w = f2bf(v.w);
    ((ushort4*)out)[i] = o;
  }
}

// ---------------- context projections + bias fold: E[64][3072] ----------------
__global__ __launch_bounds__(256) void k_ctx(
    const unsigned short* __restrict__ cjb, const unsigned short* __restrict__ heb,
    const unsigned short* __restrict__ Wchb, const unsigned short* __restrict__ Wzhb,
    const float* __restrict__ b_ih, const float* __restrict__ b_hh,
    const float* __restrict__ b_ch, const float* __restrict__ b_zh,
    float* __restrict__ E) {
  __shared__ f32x4 red[4][4][64];   // 16 KB
  int n0 = blockIdx.x * 16;         // 192 blocks
  int tid = threadIdx.x;
  int w = tid >> 6, l = tid & 63, lo = l & 15, hi = l >> 4;
  f32x4 acc[4];
#pragma unroll
  for (int r = 0; r < 4; r++) acc[r] = (f32x4){0.f, 0.f, 0.f, 0.f};
#pragma unroll 4
  for (int kk = 0; kk < 16; kk++) {
    int k = w * 512 + kk * 32;
    const unsigned short* Asrc = (k < 1024) ? cjb : heb;
    const unsigned short* Bsrc = (k < 1024) ? Wchb : Wzhb;
    int kw = (k < 1024) ? k : (k - 1024);
    int kof = kw + hi * 8;
    short8 bf = *(const short8*)(Bsrc + (size_t)(n0 + lo) * 1024 + kof);
#pragma unroll
    for (int r = 0; r < 4; r++) {
      short8 af = *(const short8*)(Asrc + (size_t)(r * 16 + lo) * 1024 + kof);
      acc[r] = mfma16(af, bf, acc[r]);
    }
  }
#pragma unroll
  for (int r = 0; r < 4; r++) red[w][r][l] = acc[r];
  __syncthreads();
  f32x4 s = red[0][w][l];
#pragma unroll
  for (int w2 = 1; w2 < 4; w2++) {
    f32x4 p = red[w2][w][l];
    s[0] += p[0]; s[1] += p[1]; s[2] += p[2]; s[3] += p[3];
  }
  int g = n0 + lo;
  float bias = b_ih[g] + b_ch[g] + b_zh[g] + ((g < 2048) ? b_hh[g] : 0.0f);
#pragma unroll
  for (int j = 0; j < 4; j++) {
    int b = w * 16 + hi * 4 + j;
    E[(size_t)b * G3 + g] = s[j] + bias;
  }
}

// ---------------- gi GEMM + E fold: giE[t*64+b][g] = X@Wih^T + E[b][g] (bf16) --------
__global__ __launch_bounds__(256) void k_gemm_gi(
    const unsigned short* __restrict__ Xb,   // [16384][1024] bf16
    const unsigned short* __restrict__ Wb,   // [3072][1024] bf16
    const float* __restrict__ E,             // [64][3072] f32
    unsigned short* __restrict__ gi) {       // [16384][3072] bf16
  __shared__ unsigned short As[128 * 32];
  __shared__ unsigned short Bs[128 * 32];
  int bid = blockIdx.x;
  int mt = bid & 127;
  int nt = bid >> 7;
  int m0 = mt * 128, n0 = nt * 128;
  int tid = threadIdx.x;
  int w = tid >> 6, l = tid & 63, lo = l & 15, hi = l >> 4;
  int wr = w >> 1, wc = w & 1;
  f32x4 acc[4][4];
#pragma unroll
  for (int i = 0; i < 4; i++)
#pragma unroll
    for (int j = 0; j < 4; j++) acc[i][j] = (f32x4){0.f, 0.f, 0.f, 0.f};
  int srow = tid >> 2;
  int scol = (tid & 3) * 8;
  for (int kt = 0; kt < 32; kt++) {
    int k0 = kt * 32;
    __syncthreads();
    gload_lds16(Xb + (size_t)(m0 + srow) * 1024 + k0 + scol, As + srow * 32 + scol);
    gload_lds16(Xb + (size_t)(m0 + 64 + srow) * 1024 + k0 + scol, As + (64 + srow) * 32 + scol);
    gload_lds16(Wb + (size_t)(n0 + srow) * 1024 + k0 + scol, Bs + srow * 32 + scol);
    gload_lds16(Wb + (size_t)(n0 + 64 + srow) * 1024 + k0 + scol, Bs + (64 + srow) * 32 + scol);
    asm volatile("s_waitcnt vmcnt(0)" ::: "memory");
    __syncthreads();
    short8 a[4], b[4];
#pragma unroll
    for (int i = 0; i < 4; i++) a[i] = *(const short8*)(As + (wr * 64 + i * 16 + lo) * 32 + hi * 8);
#pragma unroll
    for (int i = 0; i < 4; i++) b[i] = *(const short8*)(Bs + (wc * 64 + i * 16 + lo) * 32 + hi * 8);
#pragma unroll
    for (int i = 0; i < 4; i++)
#pragma unroll
      for (int j = 0; j < 4; j++) acc[i][j] = mfma16(a[i], b[j], acc[i][j]);
  }
#pragma unroll
  for (int i = 0; i < 4; i++)
#pragma unroll
    for (int j = 0; j < 4; j++)
#pragma unroll
      for (int e = 0; e < 4; e++) {
        int r = m0 + wr * 64 + i * 16 + hi * 4 + e;
        int c = n0 + wc * 64 + j * 16 + lo;
        float v = acc[i][j][e] + E[(size_t)(r & 63) * G3 + c];
        gi[(size_t)r * G3 + c] = f2bf(v);
      }
}

// ---------------- persistent recurrence kernel (v12: out-as-exchange) ----------
// 64 wgs x 128 thr (2 waves). wg cs owns cols [cs*16,+16). Wave w owns rows
// [w*32,+32) x FULL K. No barriers in the loop. Whh in LDS (96 KB).
// EXCHANGE = the f32 out tensor itself (out[t] == h(t+1), masked rows included):
//   producers bypass-store out[t] (agent scope -> MALL), drain, signal seq.
//   consumers read out[t-1] with NORMAL CACHED loads — monotonic addresses are
//   never rewritten, so caches can't be stale, and the 8 wgs per XCD share L2
//   fetches (MALL traffic 8 MB -> ~2 MB/step). f32 -> bf16 frags via cvt_pk.
// t=0 consumers read the h0 input directly (no prologue publish needed).
__global__ __launch_bounds__(128) void k_rnn(
    const unsigned short* __restrict__ giE,   // [256*64][3072] bf16 (incl E)
    const unsigned short* __restrict__ Whhb,  // [3072][1024] bf16
    const float* __restrict__ b_hh,
    const float* __restrict__ h0,             // [64][1024] f32
    const int* __restrict__ length,
    float* __restrict__ out,                  // [256][64][1024] f32 (exchange!)
    float* __restrict__ hn,                   // [64][1024] f32
    unsigned int* __restrict__ seq) {         // [128] words, 64B-spaced
  extern __shared__ char smem[];
  unsigned short* wlds = (unsigned short*)smem;   // 96 KB [96 frag=kk*3+s][64 lane][8]
  float* h0f = (float*)(smem + 98304);            // [2][16]

  const int cs = blockIdx.x, j0 = cs * 16;
  const int tid = threadIdx.x;
  const int w = tid >> 6, l = tid & 63, lo = l & 15, hi = l >> 4;
  const int rowbase = w * 32;
  const int col = j0 + lo;

  // ---- weight preload: wave w loads kk in [w*16, w*16+16) ----
#pragma unroll
  for (int k2 = 0; k2 < 16; ++k2) {
    int kk = w * 16 + k2;
#pragma unroll
    for (int s = 0; s < 3; ++s) {
      int f = kk * 3 + s;
      short8 v = *(const short8*)(Whhb + (size_t)(s * 1024 + j0 + lo) * 1024 + kk * 32 + hi * 8);
      ((short8*)wlds)[f * 64 + l] = v;
    }
  }
  const float bhhn = b_hh[2048 + col];
  float hA[4], hB[4];
  int lenA[4], lenB[4];
#pragma unroll
  for (int j = 0; j < 4; ++j) {
    int rA = rowbase + hi * 4 + j, rB = rA + 16;
    hA[j] = h0[(size_t)rA * 1024 + col]; lenA[j] = length[rA];
    hB[j] = h0[(size_t)rB * 1024 + col]; lenB[j] = length[rB];
  }
  if (w == 0 && hi == 0) h0f[lo] = hA[0];   // exact f32 h(0)[0][col]
  __syncthreads();   // init only: wlds + h0f ready
  // h(0) is the kernel input h0 — already visible everywhere; signal step-0 ready.
  if (l == 0)
    __hip_atomic_store(&seq[(cs * 2 + w) * 16], 1u, __ATOMIC_RELAXED, __HIP_MEMORY_SCOPE_AGENT);
  // ---- gir prefetch for t=0 ----
  unsigned short gir[24];
#pragma unroll
  for (int r2 = 0; r2 < 2; ++r2)
#pragma unroll
    for (int s = 0; s < 3; ++s)
#pragma unroll
      for (int j = 0; j < 4; ++j)
        gir[(r2 * 3 + s) * 4 + j] =
            giE[(size_t)(rowbase + r2 * 16 + hi * 4 + j) * G3 + s * 1024 + col];

  for (int t = 0; t < TT; ++t) {
    // ---- poll all 128 producer words (2 per lane) ----
    {
      const unsigned int* sp0 = seq + (size_t)(2 * l) * 16;
      const unsigned int* sp1 = sp0 + 16;
      unsigned int tgt = (unsigned int)(t + 1);
      for (;;) {
        unsigned int v0 = __hip_atomic_load(sp0, __ATOMIC_RELAXED, __HIP_MEMORY_SCOPE_AGENT);
        unsigned int v1 = __hip_atomic_load(sp1, __ATOMIC_RELAXED, __HIP_MEMORY_SCOPE_AGENT);
        if (__all((v0 >= tgt) && (v1 >= tgt))) break;
        __builtin_amdgcn_s_sleep(1);
      }
    }
    // ---- h source: t=0 -> h0 input; else out[t-1]. Normal cached loads. ----
    const float* src = (t == 0) ? h0 : (out + (size_t)(t - 1) * (BB * HH));
    f32x4 a00 = {0.f, 0.f, 0.f, 0.f}, a01 = a00, a02 = a00, a10 = a00, a11 = a00, a12 = a00;
#pragma unroll
    for (int kk = 0; kk < 32; ++kk) {
      const float* pA = src + (size_t)(rowbase + lo) * 1024 + kk * 32 + hi * 8;
      const float* pB = pA + 16 * 1024;
      float4 fA0 = *(const float4*)pA;
      float4 fA1 = *(const float4*)(pA + 4);
      float4 fB0 = *(const float4*)pB;
      float4 fB1 = *(const float4*)(pB + 4);
      short8 fa = pack8(fA0, fA1);
      short8 fb = pack8(fB0, fB1);
      const short8* wf = ((const short8*)wlds) + (size_t)(kk * 3) * 64 + l;
      short8 b0 = wf[0], b1 = wf[64], b2 = wf[128];
      a00 = mfma16(fa, b0, a00);
      a01 = mfma16(fa, b1, a01);
      a02 = mfma16(fa, b2, a02);
      a10 = mfma16(fb, b0, a10);
      a11 = mfma16(fb, b1, a11);
      a12 = mfma16(fb, b2, a12);
    }
    // ---- gates for 8 rows/lane ----
    float h0p = (w == 0) ? __shfl(hA[0], lo, 64) : h0f[(t & 1) * 16 + lo];
    float rA[4], rB[4];
#pragma unroll
    for (int j = 0; j < 4; ++j) {
      float R = a00[j] + bf2f(gir[0 * 4 + j]);
      float I = a01[j] + bf2f(gir[1 * 4 + j]);
      float rg = 1.f / (1.f + __expf(-R));
      float ig = 1.f / (1.f + __expf(-I));
      float nx = bf2f(gir[2 * 4 + j]) + rg * (a02[j] + bhhn);
      nx = fminf(15.f, fmaxf(-15.f, nx));
      float e2 = __expf(2.f * nx);
      float ng = (e2 - 1.f) / (e2 + 1.f);
      float hy = ng + ig * (hA[j] - ng);
      rA[j] = (t < lenA[j]) ? hy : h0p;
    }
#pragma unroll
    for (int j = 0; j < 4; ++j) {
      float R = a10[j] + bf2f(gir[(3 + 0) * 4 + j]);
      float I = a11[j] + bf2f(gir[(3 + 1) * 4 + j]);
      float rg = 1.f / (1.f + __expf(-R));
      float ig = 1.f / (1.f + __expf(-I));
      float nx = bf2f(gir[(3 + 2) * 4 + j]) + rg * (a12[j] + bhhn);
      nx = fminf(15.f, fmaxf(-15.f, nx));
      float e2 = __expf(2.f * nx);
      float ng = (e2 - 1.f) / (e2 + 1.f);
      float hy = ng + ig * (hB[j] - ng);
      rB[j] = (t < lenB[j]) ? hy : h0p;
    }
#pragma unroll
    for (int j = 0; j < 4; ++j) { hA[j] = rA[j]; hB[j] = rB[j]; }
    // ---- publish h(t+1) == out[t] via agent bypass stores (8 per lane) ----
    {
      float* dst = out + (size_t)t * (BB * HH);
#pragma unroll
      for (int j = 0; j < 4; ++j) {
        int rr = rowbase + hi * 4 + j;
        __hip_atomic_store(dst + (size_t)rr * 1024 + col, rA[j],
                           __ATOMIC_RELAXED, __HIP_MEMORY_SCOPE_AGENT);
        __hip_atomic_store(dst + (size_t)(rr + 16) * 1024 + col, rB[j],
                           __ATOMIC_RELAXED, __HIP_MEMORY_SCOPE_AGENT);
      }
    }
    if (w == 0 && hi == 0) h0f[((t + 1) & 1) * 16 + lo] = rA[0];
    if (t < TT - 1) {
      asm volatile("s_waitcnt vmcnt(0) lgkmcnt(0)" ::: "memory");
      if (l == 0)
        __hip_atomic_store(&seq[(cs * 2 + w) * 16], (unsigned int)(t + 2),
                           __ATOMIC_RELAXED, __HIP_MEMORY_SCOPE_AGENT);
      // ---- off critical path: gir(t+1) prefetch ----
      const unsigned short* gb = giE + (size_t)(t + 1) * 64 * G3;
#pragma unroll
      for (int r2 = 0; r2 < 2; ++r2)
#pragma unroll
        for (int s = 0; s < 3; ++s)
#pragma unroll
          for (int j = 0; j < 4; ++j)
            gir[(r2 * 3 + s) * 4 + j] =
                gb[(size_t)(rowbase + r2 * 16 + hi * 4 + j) * G3 + s * 1024 + col];
    } else {
      // ---- tail: hn = h(256) ----
#pragma unroll
      for (int j = 0; j < 4; ++j) {
        int rr = rowbase + hi * 4 + j;
        hn[(size_t)rr * 1024 + col] = rA[j];
        hn[(size_t)(rr + 16) * 1024 + col] = rB[j];
      }
    }
  }
}

// ---------------- host ----------------
extern "C" void kernel_launch(void* const* d_in, const int* in_sizes, int n_in,
                              void* d_out, int out_size, void* d_ws, size_t ws_size,
                              hipStream_t stream) {
  const float* input_ = (const float*)d_in[0];
  const int* length   = (const int*)d_in[1];
  const float* h0     = (const float*)d_in[2];
  const float* cj     = (const float*)d_in[3];
  const float* he     = (const float*)d_in[4];
  const float* w_ih   = (const float*)d_in[5];
  const float* w_hh   = (const float*)d_in[6];
  const float* w_ch   = (const float*)d_in[7];
  const float* w_zh   = (const float*)d_in[8];
  const float* b_ih   = (const float*)d_in[9];
  const float* b_hh   = (const float*)d_in[10];
  const float* b_ch   = (const float*)d_in[11];
  const float* b_zh   = (const float*)d_in[12];

  char* ws = (char*)d_ws;
  const size_t OFF_SEQ   = 0;               // 8 KB: 128 words, 64B-spaced
  const size_t OFF_XB    = 524288;
  const size_t OFF_WIHB  = OFF_XB + 33554432ull;
  const size_t OFF_WHHB  = OFF_WIHB + 6291456ull;
  const size_t OFF_WCHB  = OFF_WHHB + 6291456ull;
  const size_t OFF_WZHB  = OFF_WCHB + 6291456ull;
  const size_t OFF_CJB   = OFF_WZHB + 6291456ull;
  const size_t OFF_HEB   = OFF_CJB + 131072ull;
  const size_t OFF_E     = OFF_HEB + 131072ull;
  const size_t OFF_GI    = OFF_E + 786432ull;

  unsigned int* seq     = (unsigned int*)(ws + OFF_SEQ);
  unsigned short* Xb    = (unsigned short*)(ws + OFF_XB);
  unsigned short* Wihb  = (unsigned short*)(ws + OFF_WIHB);
  unsigned short* Whhb  = (unsigned short*)(ws + OFF_WHHB);
  unsigned short* Wchb  = (unsigned short*)(ws + OFF_WCHB);
  unsigned short* Wzhb  = (unsigned short*)(ws + OFF_WZHB);
  unsigned short* cjb   = (unsigned short*)(ws + OFF_CJB);
  unsigned short* heb   = (unsigned short*)(ws + OFF_HEB);
  float* E              = (float*)(ws + OFF_E);
  unsigned short* gi    = (unsigned short*)(ws + OFF_GI);

  float* out = (float*)d_out;
  float* hn  = out + 16777216;   // T*B*H

  hipFuncSetAttribute((const void*)k_rnn, hipFuncAttributeMaxDynamicSharedMemorySize, 98432);

  hipMemsetAsync(seq, 0, 16384, stream);
  k_cvt_bf16<<<2048, 256, 0, stream>>>(input_, Xb, 16777216 / 4);
  k_cvt_bf16<<<1024, 256, 0, stream>>>(w_ih, Wihb, 3145728 / 4);
  k_cvt_bf16<<<1024, 256, 0, stream>>>(w_hh, Whhb, 3145728 / 4);
  k_cvt_bf16<<<1024, 256, 0, stream>>>(w_ch, Wchb, 3145728 / 4);
  k_cvt_bf16<<<1024, 256, 0, stream>>>(w_zh, Wzhb, 3145728 / 4);
  k_cvt_bf16<<<64, 256, 0, stream>>>(cj, cjb, 65536 / 4);
  k_cvt_bf16<<<64, 256, 0, stream>>>(he, heb, 65536 / 4);
  k_ctx<<<192, 256, 0, stream>>>(cjb, heb, Wchb, Wzhb, b_ih, b_hh, b_ch, b_zh, E);
  k_gemm_gi<<<3072, 256, 0, stream>>>(Xb, Wihb, E, gi);
  k_rnn<<<64, 128, 98432, stream>>>(gi, Whhb, b_hh, h0, length, out, hn, seq);
}

// Round 13
// 1881.887 us; speedup vs baseline: 2.7695x; 2.7695x over previous
//
#include <hip/hip_runtime.h>
#include <stdint.h>

#define TT 256
#define BB 64
#define DD 1024
#define HH 1024
#define G3 3072

typedef unsigned long long ull;
typedef __attribute__((ext_vector_type(8))) short short8;
typedef __attribute__((ext_vector_type(4))) float f32x4;

__device__ __forceinline__ unsigned short f2bf(float f) {
  union { float f; unsigned int i; } v; v.f = f;
  unsigned int x = v.i;
  return (unsigned short)((x + 0x7fffu + ((x >> 16) & 1u)) >> 16);
}
__device__ __forceinline__ float bf2f(unsigned short u) {
  union { unsigned int i; float f; } v; v.i = ((unsigned int)u) << 16; return v.f;
}
__device__ __forceinline__ f32x4 mfma16(short8 a, short8 b, f32x4 c) {
  return __builtin_amdgcn_mfma_f32_16x16x32_bf16(a, b, c, 0, 0, 0);
}
__device__ __forceinline__ void gload_lds16(const void* g, void* l) {
  __builtin_amdgcn_global_load_lds((const __attribute__((address_space(1))) void*)g,
                                   (__attribute__((address_space(3))) void*)l,
                                   16, 0, 0);
}
// bypass loads (coherent from MALL). Raw asm => caller must s_waitcnt (rule #18).
__device__ __forceinline__ short8 mall_load16(const unsigned short* p) {
  short8 r;
  asm volatile("global_load_dwordx4 %0, %1, off sc0 sc1" : "=v"(r) : "v"(p));
  return r;
}
__device__ __forceinline__ float mall_loadf(const float* p) {
  float r;
  asm volatile("global_load_dword %0, %1, off sc0 sc1" : "=v"(r) : "v"(p));
  return r;
}
// chunk is stale if ANY of its 4 dwords is the 0xFFFFFFFF sentinel
// (bf16 pair 0xFFFF,0xFFFF = NaNs; h is never NaN).
__device__ __forceinline__ unsigned int chunk_stale(short8 v) {
  union { short8 s; unsigned int u[4]; } c; c.s = v;
  return (unsigned int)((c.u[0] == 0xFFFFFFFFu) | (c.u[1] == 0xFFFFFFFFu) |
                        (c.u[2] == 0xFFFFFFFFu) | (c.u[3] == 0xFFFFFFFFu));
}

// ---------------- f32 -> bf16 convert (vectorized) ----------------
__global__ void k_cvt_bf16(const float* __restrict__ in, unsigned short* __restrict__ out, int n4) {
  int i = blockIdx.x * blockDim.x + threadIdx.x;
  int stride = gridDim.x * blockDim.x;
  for (; i < n4; i += stride) {
    float4 v = ((const float4*)in)[i];
    ushort4 o;
    o.x = f2bf(v.x); o.y = f2bf(v.y); o.z = f2bf(v.z); o.w = f2bf(v.w);
    ((ushort4*)out)[i] = o;
  }
}

// ---------------- context projections + bias fold: E[64][3072] ----------------
__global__ __launch_bounds__(256) void k_ctx(
    const unsigned short* __restrict__ cjb, const unsigned short* __restrict__ heb,
    const unsigned short* __restrict__ Wchb, const unsigned short* __restrict__ Wzhb,
    const float* __restrict__ b_ih, const float* __restrict__ b_hh,
    const float* __restrict__ b_ch, const float* __restrict__ b_zh,
    float* __restrict__ E) {
  __shared__ f32x4 red[4][4][64];   // 16 KB
  int n0 = blockIdx.x * 16;         // 192 blocks
  int tid = threadIdx.x;
  int w = tid >> 6, l = tid & 63, lo = l & 15, hi = l >> 4;
  f32x4 acc[4];
#pragma unroll
  for (int r = 0; r < 4; r++) acc[r] = (f32x4){0.f, 0.f, 0.f, 0.f};
#pragma unroll 4
  for (int kk = 0; kk < 16; kk++) {
    int k = w * 512 + kk * 32;
    const unsigned short* Asrc = (k < 1024) ? cjb : heb;
    const unsigned short* Bsrc = (k < 1024) ? Wchb : Wzhb;
    int kw = (k < 1024) ? k : (k - 1024);
    int kof = kw + hi * 8;
    short8 bf = *(const short8*)(Bsrc + (size_t)(n0 + lo) * 1024 + kof);
#pragma unroll
    for (int r = 0; r < 4; r++) {
      short8 af = *(const short8*)(Asrc + (size_t)(r * 16 + lo) * 1024 + kof);
      acc[r] = mfma16(af, bf, acc[r]);
    }
  }
#pragma unroll
  for (int r = 0; r < 4; r++) red[w][r][l] = acc[r];
  __syncthreads();
  f32x4 s = red[0][w][l];
#pragma unroll
  for (int w2 = 1; w2 < 4; w2++) {
    f32x4 p = red[w2][w][l];
    s[0] += p[0]; s[1] += p[1]; s[2] += p[2]; s[3] += p[3];
  }
  int g = n0 + lo;
  float bias = b_ih[g] + b_ch[g] + b_zh[g] + ((g < 2048) ? b_hh[g] : 0.0f);
#pragma unroll
  for (int j = 0; j < 4; j++) {
    int b = w * 16 + hi * 4 + j;
    E[(size_t)b * G3 + g] = s[j] + bias;
  }
}

// ---------------- gi GEMM + E fold: giE[t*64+b][g] = X@Wih^T + E[b][g] (bf16) --------
__global__ __launch_bounds__(256) void k_gemm_gi(
    const unsigned short* __restrict__ Xb,   // [16384][1024] bf16
    const unsigned short* __restrict__ Wb,   // [3072][1024] bf16
    const float* __restrict__ E,             // [64][3072] f32
    unsigned short* __restrict__ gi) {       // [16384][3072] bf16
  __shared__ unsigned short As[128 * 32];
  __shared__ unsigned short Bs[128 * 32];
  int bid = blockIdx.x;
  int mt = bid & 127;
  int nt = bid >> 7;
  int m0 = mt * 128, n0 = nt * 128;
  int tid = threadIdx.x;
  int w = tid >> 6, l = tid & 63, lo = l & 15, hi = l >> 4;
  int wr = w >> 1, wc = w & 1;
  f32x4 acc[4][4];
#pragma unroll
  for (int i = 0; i < 4; i++)
#pragma unroll
    for (int j = 0; j < 4; j++) acc[i][j] = (f32x4){0.f, 0.f, 0.f, 0.f};
  int srow = tid >> 2;
  int scol = (tid & 3) * 8;
  for (int kt = 0; kt < 32; kt++) {
    int k0 = kt * 32;
    __syncthreads();
    gload_lds16(Xb + (size_t)(m0 + srow) * 1024 + k0 + scol, As + srow * 32 + scol);
    gload_lds16(Xb + (size_t)(m0 + 64 + srow) * 1024 + k0 + scol, As + (64 + srow) * 32 + scol);
    gload_lds16(Wb + (size_t)(n0 + srow) * 1024 + k0 + scol, Bs + srow * 32 + scol);
    gload_lds16(Wb + (size_t)(n0 + 64 + srow) * 1024 + k0 + scol, Bs + (64 + srow) * 32 + scol);
    asm volatile("s_waitcnt vmcnt(0)" ::: "memory");
    __syncthreads();
    short8 a[4], b[4];
#pragma unroll
    for (int i = 0; i < 4; i++) a[i] = *(const short8*)(As + (wr * 64 + i * 16 + lo) * 32 + hi * 8);
#pragma unroll
    for (int i = 0; i < 4; i++) b[i] = *(const short8*)(Bs + (wc * 64 + i * 16 + lo) * 32 + hi * 8);
#pragma unroll
    for (int i = 0; i < 4; i++)
#pragma unroll
      for (int j = 0; j < 4; j++) acc[i][j] = mfma16(a[i], b[j], acc[i][j]);
  }
#pragma unroll
  for (int i = 0; i < 4; i++)
#pragma unroll
    for (int j = 0; j < 4; j++)
#pragma unroll
      for (int e = 0; e < 4; e++) {
        int r = m0 + wr * 64 + i * 16 + hi * 4 + e;
        int c = n0 + wc * 64 + j * 16 + lo;
        float v = acc[i][j][e] + E[(size_t)(r & 63) * G3 + c];
        gi[(size_t)r * G3 + c] = f2bf(v);
      }
}

// ---------------- persistent recurrence kernel (v13: sentinel dataflow) --------
// 64 wgs x 256 thr (4 waves). wg cs owns cols [cs*16,+16). Wave w owns rows
// [w*16,+16) x 16 cols x FULL K=1024. NO signals, NO polls, NO drains:
// hbuf[t] is a write-once per-step buffer (pre-memset to 0xFF = bf16 NaN
// sentinel). Producers just store h(t+1) into hbuf[t+1] and move on; consumers
// bypass-load hbuf[t] chunks and retry any that still read sentinel — readiness
// travels WITH the data (one MALL RTT in steady state). hrow0[t] (f32, NaN
// sentinel) carries the exact row-0 feed for the masked branch.
__global__ __launch_bounds__(256) void k_rnn(
    const unsigned short* __restrict__ giE,   // [256*64][3072] bf16 (incl E)
    const unsigned short* __restrict__ Whhb,  // [3072][1024] bf16
    const float* __restrict__ b_hh,
    const float* __restrict__ h0,             // [64][1024] f32
    const int* __restrict__ length,
    unsigned short* __restrict__ hbuf,        // [256][64cb][64row][16] bf16 (0xFF-filled)
    float* __restrict__ hrow0,                // [256][1024] f32 (0xFF-filled)
    float* __restrict__ out,                  // [256][64][1024] f32
    float* __restrict__ hn) {                 // [64][1024] f32
  extern __shared__ char smem[];
  unsigned short* wlds = (unsigned short*)smem;   // 96 KB [32 kk][3 s][64 lane][8]

  const int cs = blockIdx.x, j0 = cs * 16;
  const int tid = threadIdx.x;
  const int w = tid >> 6, l = tid & 63, lo = l & 15, hi = l >> 4;
  const int rowbase = w * 16;
  const int col = j0 + lo;

  // ---- weight preload: wave w loads kk in [w*8, w*8+8), fragment order ----
#pragma unroll
  for (int k2 = 0; k2 < 8; ++k2) {
    int kk = w * 8 + k2;
#pragma unroll
    for (int s = 0; s < 3; ++s) {
      short8 v = *(const short8*)(Whhb + (size_t)(s * 1024 + j0 + lo) * 1024 + kk * 32 + hi * 8);
      ((short8*)wlds)[(kk * 3 + s) * 64 + l] = v;
    }
  }
  const float bhhn = b_hh[2048 + col];
  float hA[4];
  int len4[4];
#pragma unroll
  for (int j = 0; j < 4; ++j) {
    int r = rowbase + hi * 4 + j;
    hA[j] = h0[(size_t)r * 1024 + col];
    len4[j] = length[r];
  }
  // ---- prologue: publish h(0) -> hbuf[0], hrow0[0] (write-once, no drain) ----
  {
    unsigned short* dst = hbuf + (size_t)cs * 1024;
#pragma unroll
    for (int j = 0; j < 4; ++j) {
      unsigned int mine = f2bf(hA[j]);
      unsigned int oth = __shfl_xor(mine, 1, 64);
      if (!(lo & 1))
        __hip_atomic_store((unsigned int*)(dst + (rowbase + hi * 4 + j) * 16 + lo),
                           mine | (oth << 16), __ATOMIC_RELAXED, __HIP_MEMORY_SCOPE_AGENT);
    }
    if (w == 0 && hi == 0)
      __hip_atomic_store(&hrow0[col], hA[0], __ATOMIC_RELAXED, __HIP_MEMORY_SCOPE_AGENT);
  }
  __syncthreads();   // wlds ready
  // ---- gir prefetch for t=0 ----
  unsigned short gir[12];
#pragma unroll
  for (int s = 0; s < 3; ++s)
#pragma unroll
    for (int j = 0; j < 4; ++j)
      gir[s * 4 + j] = giE[(size_t)(rowbase + hi * 4 + j) * G3 + s * 1024 + col];

#define CADDR(kk) (hb + ((size_t)((kk) * 2 + (hi >> 1)) * 64 + (rowbase + lo)) * 16 + (hi & 1) * 8)

  for (int t = 0; t < TT; ++t) {
    const unsigned short* hb = hbuf + (size_t)t * 65536;
    // ---- optimistic load of all 32 chunks + row-0 feed ----
    short8 X[32];
#pragma unroll
    for (int kk = 0; kk < 32; ++kk) X[kk] = mall_load16(CADDR(kk));
    float h0p = mall_loadf(hrow0 + (size_t)t * 1024 + col);
    asm volatile("s_waitcnt vmcnt(0)" ::: "memory");
    __builtin_amdgcn_sched_barrier(0);
    // ---- sentinel retry: readiness arrives with the data ----
    for (;;) {
      unsigned int stale = 0;
#pragma unroll
      for (int kk = 0; kk < 32; ++kk) stale |= chunk_stale(X[kk]) << kk;
      bool hs = (__float_as_uint(h0p) == 0xFFFFFFFFu);
      if (__all((stale == 0) && !hs)) break;
#pragma unroll
      for (int kk = 0; kk < 32; ++kk)
        if (stale & (1u << kk)) X[kk] = mall_load16(CADDR(kk));
      if (hs) h0p = mall_loadf(hrow0 + (size_t)t * 1024 + col);
      asm volatile("s_waitcnt vmcnt(0)" ::: "memory");
      __builtin_amdgcn_sched_barrier(0);
    }
    // ---- GEMM: 16 rows x 16 cols x K=1024, W from LDS ----
    f32x4 a0 = {0.f, 0.f, 0.f, 0.f}, a1 = a0, a2 = a0;
#pragma unroll
    for (int kk = 0; kk < 32; ++kk) {
      const short8* wf = ((const short8*)wlds) + (size_t)(kk * 3) * 64 + l;
      short8 b0 = wf[0], b1 = wf[64], b2 = wf[128];
      a0 = mfma16(X[kk], b0, a0);
      a1 = mfma16(X[kk], b1, a1);
      a2 = mfma16(X[kk], b2, a2);
    }
    // ---- gates (D-layout: lane rows = rowbase + hi*4 + j, col = j0+lo) ----
    float rA[4];
#pragma unroll
    for (int j = 0; j < 4; ++j) {
      float R = a0[j] + bf2f(gir[0 * 4 + j]);
      float I = a1[j] + bf2f(gir[1 * 4 + j]);
      float rg = 1.f / (1.f + __expf(-R));
      float ig = 1.f / (1.f + __expf(-I));
      float nx = bf2f(gir[2 * 4 + j]) + rg * (a2[j] + bhhn);
      nx = fminf(15.f, fmaxf(-15.f, nx));
      float e2 = __expf(2.f * nx);
      float ng = (e2 - 1.f) / (e2 + 1.f);
      float hy = ng + ig * (hA[j] - ng);
      rA[j] = (t < len4[j]) ? hy : h0p;
    }
#pragma unroll
    for (int j = 0; j < 4; ++j) hA[j] = rA[j];
    if (t < TT - 1) {
      // ---- publish h(t+1) (no drain, no signal) ----
      unsigned short* dst = hbuf + (size_t)(t + 1) * 65536 + (size_t)cs * 1024;
#pragma unroll
      for (int j = 0; j < 4; ++j) {
        unsigned int mine = f2bf(rA[j]);
        unsigned int oth = __shfl_xor(mine, 1, 64);
        if (!(lo & 1))
          __hip_atomic_store((unsigned int*)(dst + (rowbase + hi * 4 + j) * 16 + lo),
                             mine | (oth << 16), __ATOMIC_RELAXED, __HIP_MEMORY_SCOPE_AGENT);
      }
      if (w == 0 && hi == 0)
        __hip_atomic_store(&hrow0[(size_t)(t + 1) * 1024 + col], rA[0],
                           __ATOMIC_RELAXED, __HIP_MEMORY_SCOPE_AGENT);
      // ---- off critical path: out(t) + gir(t+1) ----
#pragma unroll
      for (int j = 0; j < 4; ++j)
        out[(size_t)t * (BB * HH) + (size_t)(rowbase + hi * 4 + j) * 1024 + col] = rA[j];
      const unsigned short* gb = giE + (size_t)(t + 1) * 64 * G3;
#pragma unroll
      for (int s = 0; s < 3; ++s)
#pragma unroll
        for (int j = 0; j < 4; ++j)
          gir[s * 4 + j] = gb[(size_t)(rowbase + hi * 4 + j) * G3 + s * 1024 + col];
    } else {
#pragma unroll
      for (int j = 0; j < 4; ++j) {
        int r = rowbase + hi * 4 + j;
        out[(size_t)t * (BB * HH) + (size_t)r * 1024 + col] = rA[j];
        hn[(size_t)r * 1024 + col] = rA[j];
      }
    }
  }
#undef CADDR
}

// ---------------- host ----------------
extern "C" void kernel_launch(void* const* d_in, const int* in_sizes, int n_in,
                              void* d_out, int out_size, void* d_ws, size_t ws_size,
                              hipStream_t stream) {
  const float* input_ = (const float*)d_in[0];
  const int* length   = (const int*)d_in[1];
  const float* h0     = (const float*)d_in[2];
  const float* cj     = (const float*)d_in[3];
  const float* he     = (const float*)d_in[4];
  const float* w_ih   = (const float*)d_in[5];
  const float* w_hh   = (const float*)d_in[6];
  const float* w_ch   = (const float*)d_in[7];
  const float* w_zh   = (const float*)d_in[8];
  const float* b_ih   = (const float*)d_in[9];
  const float* b_hh   = (const float*)d_in[10];
  const float* b_ch   = (const float*)d_in[11];
  const float* b_zh   = (const float*)d_in[12];

  char* ws = (char*)d_ws;
  const size_t OFF_HBUF  = 0;                   // 32 MB: [256][64][64][16] ushort
  const size_t OFF_HROW0 = 33554432ull;         // 1 MB: [256][1024] f32
  const size_t OFF_XB    = 34603008ull;         // 32 MB
  const size_t OFF_WIHB  = OFF_XB + 33554432ull;
  const size_t OFF_WHHB  = OFF_WIHB + 6291456ull;
  const size_t OFF_WCHB  = OFF_WHHB + 6291456ull;
  const size_t OFF_WZHB  = OFF_WCHB + 6291456ull;
  const size_t OFF_CJB   = OFF_WZHB + 6291456ull;
  const size_t OFF_HEB   = OFF_CJB + 131072ull;
  const size_t OFF_E     = OFF_HEB + 131072ull;
  const size_t OFF_GI    = OFF_E + 786432ull;   // 96 MB

  unsigned short* hbuf  = (unsigned short*)(ws + OFF_HBUF);
  float* hrow0          = (float*)(ws + OFF_HROW0);
  unsigned short* Xb    = (unsigned short*)(ws + OFF_XB);
  unsigned short* Wihb  = (unsigned short*)(ws + OFF_WIHB);
  unsigned short* Whhb  = (unsigned short*)(ws + OFF_WHHB);
  unsigned short* Wchb  = (unsigned short*)(ws + OFF_WCHB);
  unsigned short* Wzhb  = (unsigned short*)(ws + OFF_WZHB);
  unsigned short* cjb   = (unsigned short*)(ws + OFF_CJB);
  unsigned short* heb   = (unsigned short*)(ws + OFF_HEB);
  float* E              = (float*)(ws + OFF_E);
  unsigned short* gi    = (unsigned short*)(ws + OFF_GI);

  float* out = (float*)d_out;
  float* hn  = out + 16777216;   // T*B*H

  hipFuncSetAttribute((const void*)k_rnn, hipFuncAttributeMaxDynamicSharedMemorySize, 98304);

  // sentinel-fill the dataflow buffers (hbuf + hrow0 are contiguous)
  hipMemsetAsync(ws + OFF_HBUF, 0xFF, 33554432ull + 1048576ull, stream);
  k_cvt_bf16<<<2048, 256, 0, stream>>>(input_, Xb, 16777216 / 4);
  k_cvt_bf16<<<1024, 256, 0, stream>>>(w_ih, Wihb, 3145728 / 4);
  k_cvt_bf16<<<1024, 256, 0, stream>>>(w_hh, Whhb, 3145728 / 4);
  k_cvt_bf16<<<1024, 256, 0, stream>>>(w_ch, Wchb, 3145728 / 4);
  k_cvt_bf16<<<1024, 256, 0, stream>>>(w_zh, Wzhb, 3145728 / 4);
  k_cvt_bf16<<<64, 256, 0, stream>>>(cj, cjb, 65536 / 4);
  k_cvt_bf16<<<64, 256, 0, stream>>>(he, heb, 65536 / 4);
  k_ctx<<<192, 256, 0, stream>>>(cjb, heb, Wchb, Wzhb, b_ih, b_hh, b_ch, b_zh, E);
  k_gemm_gi<<<3072, 256, 0, stream>>>(Xb, Wihb, E, gi);
  k_rnn<<<64, 256, 98304, stream>>>(gi, Whhb, b_hh, h0, length, hbuf, hrow0, out, hn);
}